// Round 3
// baseline (4209.888 us; speedup 1.0000x reference)
//
#include <hip/hip_runtime.h>
#include <hip/hip_cooperative_groups.h>

namespace cg = cooperative_groups;

typedef __attribute__((ext_vector_type(8))) short bf16x8;
typedef __attribute__((ext_vector_type(4))) float f32x4;

__device__ __forceinline__ float sigf(float x){ return 1.0f/(1.0f + expf(-x)); }

__device__ __forceinline__ short f2bf(float x){
  union { float f; unsigned u; } v; v.f = x;
  unsigned r = v.u + 0x7fffu + ((v.u >> 16) & 1u);
  return (short)(r >> 16);
}

// ---------------- k_zero: zero LEVCNT, MAXLEV, HG
__global__ __launch_bounds__(512) void k_zero(short* __restrict__ HG, int* __restrict__ LEVCNT,
                                              int* __restrict__ MAXLEV){
  for (int i = threadIdx.x; i < 32768; i += 512) HG[i] = 0;
  if (threadIdx.x < 64) LEVCNT[threadIdx.x] = 0;
  if (threadIdx.x == 64) MAXLEV[0] = 0;
}

// ---------------- k_cvtw: tl_w f32 -> bf16 (6144x3072)
__global__ __launch_bounds__(256) void k_cvtw(const float* __restrict__ tl_w,
                                              short* __restrict__ TLWB){
  int i = blockIdx.x*256 + threadIdx.x;       // each handles 8 elems
  int base = i*8;
  if (base >= 6144*3072) return;
  float4 a = *(const float4*)(tl_w + base);
  float4 b = *(const float4*)(tl_w + base + 4);
  bf16x8 o;
  o[0]=f2bf(a.x); o[1]=f2bf(a.y); o[2]=f2bf(a.z); o[3]=f2bf(a.w);
  o[4]=f2bf(b.x); o[5]=f2bf(b.y); o[6]=f2bf(b.z); o[7]=f2bf(b.w);
  *(bf16x8*)(TLWB + base) = o;
}

// ---------------- k_rank
__global__ __launch_bounds__(128) void k_rank(const float* __restrict__ emb,
                                              const float* __restrict__ w1,
                                              const float* __restrict__ w2,
                                              float* __restrict__ SC){
  int bl = blockIdx.x;
  int j  = threadIdx.x;
  const float* e = emb + bl*1024;
  const float* w = w1 + j*1024;
  float acc = 0.f;
  for (int k = 0; k < 1024; k += 4){
    float4 ev = *(const float4*)(e + k);
    float4 wv = *(const float4*)(w + k);
    acc += ev.x*wv.x + ev.y*wv.y + ev.z*wv.z + ev.w*wv.w;
  }
  float s = fmaxf(acc, 0.f) * w2[j];
  __shared__ float red[128];
  red[j] = s;
  __syncthreads();
  for (int st = 64; st > 0; st >>= 1){
    if (j < st) red[j] += red[j + st];
    __syncthreads();
  }
  if (j == 0) SC[bl] = red[0];
}

// ---------------- k_gx (MFMA bf16): GX[bl][r] = emb[bl]·w_ih[r] + b_ih[r] + b_hh[r]
__global__ __launch_bounds__(256) void k_gx(const float* __restrict__ emb,
                                            const float* __restrict__ w_ih,
                                            const float* __restrict__ b_ih,
                                            const float* __restrict__ b_hh,
                                            float* __restrict__ GX){
  __shared__ short Ws[64][72];
  __shared__ short Es[64][72];
  int mt = blockIdx.x >> 4;
  int nt4 = blockIdx.x & 15;
  int r0 = mt*64, n0 = nt4*64;
  int lane = threadIdx.x & 63, w = threadIdx.x >> 6;
  int m16 = lane & 15, quad = lane >> 4;
  int srr = threadIdx.x >> 2, skk = (threadIdx.x & 3)*16;
  f32x4 acc[4] = {{0,0,0,0},{0,0,0,0},{0,0,0,0},{0,0,0,0}};
  for (int k0 = 0; k0 < 1024; k0 += 64){
    #pragma unroll
    for (int i = 0; i < 4; i++){
      float4 v = *(const float4*)(w_ih + (r0 + srr)*1024 + k0 + skk + i*4);
      Ws[srr][skk + i*4 + 0] = f2bf(v.x); Ws[srr][skk + i*4 + 1] = f2bf(v.y);
      Ws[srr][skk + i*4 + 2] = f2bf(v.z); Ws[srr][skk + i*4 + 3] = f2bf(v.w);
      float4 u = *(const float4*)(emb + (n0 + srr)*1024 + k0 + skk + i*4);
      Es[srr][skk + i*4 + 0] = f2bf(u.x); Es[srr][skk + i*4 + 1] = f2bf(u.y);
      Es[srr][skk + i*4 + 2] = f2bf(u.z); Es[srr][skk + i*4 + 3] = f2bf(u.w);
    }
    __syncthreads();
    #pragma unroll
    for (int ks = 0; ks < 64; ks += 32){
      bf16x8 a = *(bf16x8*)&Ws[w*16 + m16][ks + quad*8];
      #pragma unroll
      for (int nt = 0; nt < 4; nt++){
        bf16x8 b = *(bf16x8*)&Es[nt*16 + m16][ks + quad*8];
        acc[nt] = __builtin_amdgcn_mfma_f32_16x16x32_bf16(a, b, acc[nt], 0, 0, 0);
      }
    }
    __syncthreads();
  }
  int rbase = r0 + w*16 + quad*4;
  f32x4 bi = *(const f32x4*)(b_ih + rbase);
  f32x4 bh = *(const f32x4*)(b_hh + rbase);
  #pragma unroll
  for (int nt = 0; nt < 4; nt++){
    int n = n0 + nt*16 + m16;
    f32x4 o = acc[nt] + bi + bh;
    *(f32x4*)(GX + n*4096 + rbase) = o;
  }
}

// ---------------- k_build: per-sentence greedy tree, levels, level lists, lps, maxlev
__global__ __launch_bounds__(64) void k_build(const float* __restrict__ SC,
                                              const int* __restrict__ length,
                                              int* __restrict__ LCH, int* __restrict__ RCH,
                                              int* __restrict__ LEVCNT, int* __restrict__ LEVLIST,
                                              int* __restrict__ ROOTP, int* __restrict__ MAXLEV,
                                              float* __restrict__ OUT){
  __shared__ float scl[64];
  __shared__ int stk_s[64], stk_e[64], order_l[64];
  __shared__ int isn_l[64], lev_l[64], ns_l[64], ne_l[64];
  int b = blockIdx.x;
  if (threadIdx.x < 64){
    scl[threadIdx.x] = SC[b*64 + threadIdx.x];
    isn_l[threadIdx.x] = 0;
  }
  __syncthreads();
  if (threadIdx.x == 0){
    int len = length[b];
    int cnt = 0, sp = 0;
    if (len >= 2){ stk_s[0] = 0; stk_e[0] = len; sp = 1; }
    while (sp > 0){
      sp--;
      int s = stk_s[sp], e = stk_e[sp];
      int pos = s; float mx = scl[s];
      for (int q = s+1; q < e; q++){ if (scl[q] > mx){ mx = scl[q]; pos = q; } }
      order_l[cnt++] = pos;
      int lq;
      if (pos - s <= 0) lq = -1;
      else if (pos - s == 1) lq = s;
      else { lq = s; float m2 = scl[s]; for (int q = s+1; q < pos; q++){ if (scl[q] > m2){ m2 = scl[q]; lq = q; } } }
      int rq;
      if (e - (pos+1) <= 0) rq = -1;
      else if (e - (pos+1) == 1) rq = pos+1;
      else { rq = pos+1; float m2 = scl[pos+1]; for (int q = pos+2; q < e; q++){ if (scl[q] > m2){ m2 = scl[q]; rq = q; } } }
      LCH[b*64 + pos] = lq; RCH[b*64 + pos] = rq;
      ns_l[pos] = s; ne_l[pos] = e; isn_l[pos] = 1;
      if (pos - s >= 2){ stk_s[sp] = s; stk_e[sp] = pos; sp++; }
      if (e - pos - 1 >= 2){ stk_s[sp] = pos+1; stk_e[sp] = e; sp++; }
    }
    for (int i = cnt-1; i >= 0; i--){
      int p = order_l[i];
      int lv = 0;
      int lq = LCH[b*64 + p];
      if (lq >= 0 && isn_l[lq]) lv = lev_l[lq] + 1;
      int rq = RCH[b*64 + p];
      if (rq >= 0 && isn_l[rq] && lev_l[rq] + 1 > lv) lv = lev_l[rq] + 1;
      lev_l[p] = lv;
      int slot = atomicAdd(&LEVCNT[lv], 1);
      LEVLIST[lv*512 + slot] = (b << 8) | p;
    }
    float lp = 0.f;
    for (int i = 0; i < cnt; i++){
      int p = order_l[i];
      int s = ns_l[p], e = ne_l[p];
      float mx = scl[s];
      for (int q = s+1; q < e; q++) mx = fmaxf(mx, scl[q]);
      float sum = 0.f;
      for (int q = s; q < e; q++) sum += expf(scl[q] - mx);
      lp += (float)(e - s) * (scl[p] - (mx + logf(sum)));
    }
    OUT[32768 + b] = lp;
    int rp;
    if (len <= 1) rp = 0;
    else { rp = 0; float m2 = scl[0]; for (int q = 1; q < len; q++){ if (scl[q] > m2){ m2 = scl[q]; rp = q; } } }
    ROOTP[b] = rp;
    if (cnt > 0) atomicMax(MAXLEV, lev_l[order_l[0]]);
  }
}

// ---------------- k_lstm (cooperative, 32 blocks x 512): all 64 steps, weights in registers
// block bi: j in [bi*32, bi*32+32). wave w (0..7): gate=w>>1, jhalf=w&1,
// rows = gate*1024 + j0 + jhalf*16 + m16. MFMA A=W(16 rows x K=1024 bf16 regs), B=h(16 b).
__global__ __launch_bounds__(512, 2) void k_lstm(const float* __restrict__ w_hh,
      const float* __restrict__ GX, float* __restrict__ HS, float* __restrict__ CS,
      short* __restrict__ HG){
  cg::grid_group gg = cg::this_grid();
  __shared__ float EX[4][32][17];
  int bi = blockIdx.x;
  int w = threadIdx.x >> 6, lane = threadIdx.x & 63;
  int quad = lane >> 4, m16 = lane & 15;
  int gate = w >> 1, jhalf = w & 1;
  int j0 = bi*32;
  int row = gate*1024 + j0 + jhalf*16 + m16;
  // preload weights into registers as bf16 A-fragments
  bf16x8 Wf[32];
  #pragma unroll
  for (int ks = 0; ks < 32; ks++){
    const float* p = w_hh + row*1024 + ks*32 + quad*8;
    float4 a = *(const float4*)p;
    float4 b = *(const float4*)(p + 4);
    bf16x8 o;
    o[0]=f2bf(a.x); o[1]=f2bf(a.y); o[2]=f2bf(a.z); o[3]=f2bf(a.w);
    o[4]=f2bf(b.x); o[5]=f2bf(b.y); o[6]=f2bf(b.z); o[7]=f2bf(b.w);
    Wf[ks] = o;
  }
  // owner mapping: lane tid -> (jloc, b)
  int tid = threadIdx.x;
  int ojl = tid >> 4, ob = tid & 15;
  int oj = j0 + ojl;
  float creg = 0.f;
  int jloc_base = jhalf*16 + quad*4;
  for (int t = 0; t < 64; t++){
    const short* HR = HG + (t & 1)*16384;
    short* HW = HG + ((t + 1) & 1)*16384;
    f32x4 acc = {0.f, 0.f, 0.f, 0.f};
    #pragma unroll
    for (int ks = 0; ks < 32; ks++){
      bf16x8 bf = *(const bf16x8*)(HR + (ks*4 + quad)*128 + m16*8);
      acc = __builtin_amdgcn_mfma_f32_16x16x32_bf16(Wf[ks], bf, acc, 0, 0, 0);
    }
    #pragma unroll
    for (int r = 0; r < 4; r++) EX[gate][jloc_base + r][m16] = acc[r];
    __syncthreads();
    // owner computes gates -> c,h
    const float* gx = GX + (ob*64 + t)*4096 + oj;
    float gi = EX[0][ojl][ob] + gx[0];
    float gf = EX[1][ojl][ob] + gx[1024];
    float gu = EX[2][ojl][ob] + gx[2048];
    float go = EX[3][ojl][ob] + gx[3072];
    float cc = sigf(gf)*creg + sigf(gi)*tanhf(gu);
    float hh = sigf(go)*tanhf(cc);
    creg = cc;
    HS[(ob*64 + t)*1024 + oj] = hh;
    CS[(ob*64 + t)*1024 + oj] = cc;
    HW[(oj >> 3)*128 + ob*8 + (oj & 7)] = f2bf(hh);
    __threadfence();
    gg.sync();
  }
}

// ---------------- k_tree (cooperative, 384 blocks x 256): all levels
__global__ __launch_bounds__(256, 2) void k_tree(const short* __restrict__ TLWB,
      const float* __restrict__ tl_b,
      float* __restrict__ HS, float* __restrict__ CS,
      const int* __restrict__ LCH, const int* __restrict__ RCH,
      const int* __restrict__ LEVCNT, const int* __restrict__ LEVLIST,
      const int* __restrict__ MAXLEV, float* __restrict__ G){
  cg::grid_group gg = cg::this_grid();
  __shared__ short Ws[64][72];
  __shared__ short Hs[64][72];
  __shared__ int nb[64], nq0[64], nq1[64], nq2[64];
  int maxlev = MAXLEV[0];
  int lane = threadIdx.x & 63, w = threadIdx.x >> 6;
  int m16 = lane & 15, quad = lane >> 4;
  int srr = threadIdx.x >> 2, skk = (threadIdx.x & 3)*16;
  for (int v = 0; v <= maxlev; v++){
    int nc = LEVCNT[v];
    int ntiles = (nc + 63) >> 6;
    int ntasks = ntiles * 96;
    for (int task = blockIdx.x; task < ntasks; task += gridDim.x){
      int r0 = (task % 96)*64;
      int n0 = (task / 96)*64;
      if (threadIdx.x < 64){
        int n = n0 + threadIdx.x;
        if (n < nc){
          int e = LEVLIST[v*512 + n];
          int bb = e >> 8, p = e & 255;
          nb[threadIdx.x] = bb;
          nq0[threadIdx.x] = LCH[bb*64 + p];
          nq1[threadIdx.x] = RCH[bb*64 + p];
          nq2[threadIdx.x] = p;
        } else {
          nb[threadIdx.x] = -1; nq0[threadIdx.x] = -1;
          nq1[threadIdx.x] = -1; nq2[threadIdx.x] = -1;
        }
      }
      __syncthreads();
      f32x4 acc[4] = {{0,0,0,0},{0,0,0,0},{0,0,0,0},{0,0,0,0}};
      for (int k0 = 0; k0 < 3072; k0 += 64){
        // stage A tile (bf16 direct)
        *(bf16x8*)&Ws[srr][skk]     = *(const bf16x8*)(TLWB + (r0 + srr)*3072 + k0 + skk);
        *(bf16x8*)&Ws[srr][skk + 8] = *(const bf16x8*)(TLWB + (r0 + srr)*3072 + k0 + skk + 8);
        // stage B tile from HS with node indirection
        int seg = k0 >> 10;
        int ko = (k0 & 1023) + skk;
        {
          int nl = srr;
          int bb = nb[nl];
          int q = (seg == 0) ? nq0[nl] : (seg == 1) ? nq1[nl] : nq2[nl];
          if (bb >= 0 && q >= 0){
            const float* hp = HS + (bb*64 + q)*1024 + ko;
            float4 a0 = *(const float4*)hp;
            float4 a1 = *(const float4*)(hp + 4);
            float4 a2 = *(const float4*)(hp + 8);
            float4 a3 = *(const float4*)(hp + 12);
            bf16x8 o0, o1;
            o0[0]=f2bf(a0.x); o0[1]=f2bf(a0.y); o0[2]=f2bf(a0.z); o0[3]=f2bf(a0.w);
            o0[4]=f2bf(a1.x); o0[5]=f2bf(a1.y); o0[6]=f2bf(a1.z); o0[7]=f2bf(a1.w);
            o1[0]=f2bf(a2.x); o1[1]=f2bf(a2.y); o1[2]=f2bf(a2.z); o1[3]=f2bf(a2.w);
            o1[4]=f2bf(a3.x); o1[5]=f2bf(a3.y); o1[6]=f2bf(a3.z); o1[7]=f2bf(a3.w);
            *(bf16x8*)&Hs[nl][skk]     = o0;
            *(bf16x8*)&Hs[nl][skk + 8] = o1;
          } else {
            bf16x8 z = {0,0,0,0,0,0,0,0};
            *(bf16x8*)&Hs[nl][skk]     = z;
            *(bf16x8*)&Hs[nl][skk + 8] = z;
          }
        }
        __syncthreads();
        #pragma unroll
        for (int ks = 0; ks < 64; ks += 32){
          bf16x8 a = *(bf16x8*)&Ws[w*16 + m16][ks + quad*8];
          #pragma unroll
          for (int nt = 0; nt < 4; nt++){
            bf16x8 b = *(bf16x8*)&Hs[nt*16 + m16][ks + quad*8];
            acc[nt] = __builtin_amdgcn_mfma_f32_16x16x32_bf16(a, b, acc[nt], 0, 0, 0);
          }
        }
        __syncthreads();
      }
      int rbase = r0 + w*16 + quad*4;
      #pragma unroll
      for (int nt = 0; nt < 4; nt++){
        int n = n0 + nt*16 + m16;
        if (n < nc) *(f32x4*)(G + n*6144 + rbase) = acc[nt];
      }
      __syncthreads();
    }
    __threadfence();
    gg.sync();
    // update stage
    int total = nc * 1024;
    for (int idx = blockIdx.x*256 + threadIdx.x; idx < total; idx += gridDim.x*256){
      int n = idx >> 10, j = idx & 1023;
      int e = LEVLIST[v*512 + n];
      int b = e >> 8, p = e & 255;
      const float* g = G + n*6144;
      float gi  = g[j]        + tl_b[j];
      float gfl = g[1024 + j] + tl_b[1024 + j];
      float gfr = g[2048 + j] + tl_b[2048 + j];
      float gfm = g[3072 + j] + tl_b[3072 + j];
      float gu  = g[4096 + j] + tl_b[4096 + j];
      float go  = g[5120 + j] + tl_b[5120 + j];
      int lq = LCH[b*64 + p], rq = RCH[b*64 + p];
      float cl = (lq >= 0) ? CS[(b*64 + lq)*1024 + j] : 0.f;
      float cr = (rq >= 0) ? CS[(b*64 + rq)*1024 + j] : 0.f;
      float cm = CS[(b*64 + p)*1024 + j];
      float c = sigf(gfl)*cl + sigf(gfr)*cr + sigf(gfm)*cm + sigf(gi)*tanhf(gu);
      float h = sigf(go)*tanhf(c);
      HS[(b*64 + p)*1024 + j] = h;
      CS[(b*64 + p)*1024 + j] = c;
    }
    __threadfence();
    gg.sync();
  }
}

// ---------------- k_root
__global__ __launch_bounds__(256) void k_root(const int* __restrict__ ROOTP,
      const float* __restrict__ HS, const float* __restrict__ CS,
      float* __restrict__ OUT){
  int idx = blockIdx.x*256 + threadIdx.x;
  int b = idx >> 10, j = idx & 1023;
  int rp = ROOTP[b];
  OUT[b*1024 + j]         = HS[(b*64 + rp)*1024 + j];
  OUT[16384 + b*1024 + j] = CS[(b*64 + rp)*1024 + j];
}

extern "C" void kernel_launch(void* const* d_in, const int* in_sizes, int n_in,
                              void* d_out, int out_size, void* d_ws, size_t ws_size,
                              hipStream_t stream) {
  (void)in_sizes; (void)n_in; (void)out_size; (void)ws_size;
  const float* emb    = (const float*)d_in[0];
  const int*   length = (const int*)  d_in[2];
  const float* w_ih   = (const float*)d_in[3];
  const float* w_hh   = (const float*)d_in[4];
  const float* b_ih   = (const float*)d_in[5];
  const float* b_hh   = (const float*)d_in[6];
  const float* tl_w   = (const float*)d_in[7];
  const float* tl_b   = (const float*)d_in[8];
  const float* rk_w1  = (const float*)d_in[9];
  const float* rk_w2  = (const float*)d_in[10];
  float* OUT = (float*)d_out;

  float* ws_f = (float*)d_ws;
  short* TLWB = (short*)ws_f;               // 18,874,368 shorts = 9,437,184 f
  float* GX   = ws_f + 9437184;             // 4,194,304 f (reused as G by tree)
  float* HS   = ws_f + 13631488;            // 1,048,576 f
  float* CS   = ws_f + 14680064;            // 1,048,576 f
  float* SC   = ws_f + 15728640;            // 1,024 f
  short* HG   = (short*)(ws_f + 15729664);  // 32,768 shorts (2 x 16384)
  int*   IW   = (int*)(ws_f + 15746048);
  int* LCH     = IW;
  int* RCH     = IW + 1024;
  int* LEVCNT  = IW + 2048;
  int* LEVLIST = IW + 2112;
  int* ROOTP   = IW + 34880;
  int* MAXLEV  = IW + 34896;
  float* G = GX;

  k_zero<<<1, 512, 0, stream>>>(HG, LEVCNT, MAXLEV);
  k_cvtw<<<9216, 256, 0, stream>>>(tl_w, TLWB);
  k_rank<<<1024, 128, 0, stream>>>(emb, rk_w1, rk_w2, SC);
  k_gx<<<1024, 256, 0, stream>>>(emb, w_ih, b_ih, b_hh, GX);
  k_build<<<16, 64, 0, stream>>>(SC, length, LCH, RCH, LEVCNT, LEVLIST, ROOTP, MAXLEV, OUT);

  {
    void* args[] = { (void*)&w_hh, (void*)&GX, (void*)&HS, (void*)&CS, (void*)&HG };
    hipLaunchCooperativeKernel((const void*)k_lstm, dim3(32), dim3(512), args, 0, stream);
  }
  {
    void* args[] = { (void*)&TLWB, (void*)&tl_b, (void*)&HS, (void*)&CS,
                     (void*)&LCH, (void*)&RCH, (void*)&LEVCNT, (void*)&LEVLIST,
                     (void*)&MAXLEV, (void*)&G };
    hipLaunchCooperativeKernel((const void*)k_tree, dim3(384), dim3(256), args, 0, stream);
  }
  k_root<<<64, 256, 0, stream>>>(ROOTP, HS, CS, OUT);
}

// Round 5
// 2165.827 us; speedup vs baseline: 1.9438x; 1.9438x over previous
//
#include <hip/hip_runtime.h>

typedef __attribute__((ext_vector_type(8))) short bf16x8;
typedef __attribute__((ext_vector_type(4))) float f32x4;

__device__ __forceinline__ float sigf(float x){ return 1.0f/(1.0f + expf(-x)); }

__device__ __forceinline__ short f2bf(float x){
  union { float f; unsigned u; } v; v.f = x;
  unsigned r = v.u + 0x7fffu + ((v.u >> 16) & 1u);
  return (short)(r >> 16);
}

// Lightweight agent-scope grid barrier: monotone counter, leader-spin.
// All blocks must be co-resident (cooperative launch) and call it the same
// number of times. Counter MUST be zeroed before the kernel runs.
__device__ __forceinline__ void gridbar(int* cnt, int nb, int* phase){
  __syncthreads();
  if (threadIdx.x == 0){
    __threadfence();   // release: make this block's writes visible (L2)
    __hip_atomic_fetch_add(cnt, 1, __ATOMIC_RELEASE, __HIP_MEMORY_SCOPE_AGENT);
    int tgt = (*phase) * nb + nb;
    while (__hip_atomic_load(cnt, __ATOMIC_RELAXED, __HIP_MEMORY_SCOPE_AGENT) < tgt)
      __builtin_amdgcn_s_sleep(1);
    __threadfence();   // acquire: invalidate stale L1 lines
  }
  __syncthreads();
  (*phase) += 1;
}

// ---------------- k_zero: zero HG, LEVCNT, MAXLEV, both barrier counters
__global__ __launch_bounds__(512) void k_zero(short* __restrict__ HG, int* __restrict__ LEVCNT,
                                              int* __restrict__ MAXLEV,
                                              int* __restrict__ BAR1, int* __restrict__ BAR2){
  for (int i = threadIdx.x; i < 32768; i += 512) HG[i] = 0;
  if (threadIdx.x < 64) LEVCNT[threadIdx.x] = 0;
  if (threadIdx.x == 64) MAXLEV[0] = 0;
  if (threadIdx.x == 65) BAR1[0] = 0;
  if (threadIdx.x == 66) BAR2[0] = 0;
}

// ---------------- k_cvtw: tl_w f32 -> bf16 (6144x3072)
__global__ __launch_bounds__(256) void k_cvtw(const float* __restrict__ tl_w,
                                              short* __restrict__ TLWB){
  int i = blockIdx.x*256 + threadIdx.x;
  int base = i*8;
  if (base >= 6144*3072) return;
  float4 a = *(const float4*)(tl_w + base);
  float4 b = *(const float4*)(tl_w + base + 4);
  bf16x8 o;
  o[0]=f2bf(a.x); o[1]=f2bf(a.y); o[2]=f2bf(a.z); o[3]=f2bf(a.w);
  o[4]=f2bf(b.x); o[5]=f2bf(b.y); o[6]=f2bf(b.z); o[7]=f2bf(b.w);
  *(bf16x8*)(TLWB + base) = o;
}

// ---------------- k_rank
__global__ __launch_bounds__(128) void k_rank(const float* __restrict__ emb,
                                              const float* __restrict__ w1,
                                              const float* __restrict__ w2,
                                              float* __restrict__ SC){
  int bl = blockIdx.x;
  int j  = threadIdx.x;
  const float* e = emb + bl*1024;
  const float* w = w1 + j*1024;
  float acc = 0.f;
  for (int k = 0; k < 1024; k += 4){
    float4 ev = *(const float4*)(e + k);
    float4 wv = *(const float4*)(w + k);
    acc += ev.x*wv.x + ev.y*wv.y + ev.z*wv.z + ev.w*wv.w;
  }
  float s = fmaxf(acc, 0.f) * w2[j];
  __shared__ float red[128];
  red[j] = s;
  __syncthreads();
  for (int st = 64; st > 0; st >>= 1){
    if (j < st) red[j] += red[j + st];
    __syncthreads();
  }
  if (j == 0) SC[bl] = red[0];
}

// ---------------- k_gx (MFMA bf16): GX[bl][r] = emb[bl]·w_ih[r] + b_ih[r] + b_hh[r]
__global__ __launch_bounds__(256) void k_gx(const float* __restrict__ emb,
                                            const float* __restrict__ w_ih,
                                            const float* __restrict__ b_ih,
                                            const float* __restrict__ b_hh,
                                            float* __restrict__ GX){
  __shared__ short Ws[64][72];
  __shared__ short Es[64][72];
  int mt = blockIdx.x >> 4;
  int nt4 = blockIdx.x & 15;
  int r0 = mt*64, n0 = nt4*64;
  int lane = threadIdx.x & 63, w = threadIdx.x >> 6;
  int m16 = lane & 15, quad = lane >> 4;
  int srr = threadIdx.x >> 2, skk = (threadIdx.x & 3)*16;
  f32x4 acc[4] = {{0,0,0,0},{0,0,0,0},{0,0,0,0},{0,0,0,0}};
  for (int k0 = 0; k0 < 1024; k0 += 64){
    #pragma unroll
    for (int i = 0; i < 4; i++){
      float4 v = *(const float4*)(w_ih + (r0 + srr)*1024 + k0 + skk + i*4);
      Ws[srr][skk + i*4 + 0] = f2bf(v.x); Ws[srr][skk + i*4 + 1] = f2bf(v.y);
      Ws[srr][skk + i*4 + 2] = f2bf(v.z); Ws[srr][skk + i*4 + 3] = f2bf(v.w);
      float4 u = *(const float4*)(emb + (n0 + srr)*1024 + k0 + skk + i*4);
      Es[srr][skk + i*4 + 0] = f2bf(u.x); Es[srr][skk + i*4 + 1] = f2bf(u.y);
      Es[srr][skk + i*4 + 2] = f2bf(u.z); Es[srr][skk + i*4 + 3] = f2bf(u.w);
    }
    __syncthreads();
    #pragma unroll
    for (int ks = 0; ks < 64; ks += 32){
      bf16x8 a = *(bf16x8*)&Ws[w*16 + m16][ks + quad*8];
      #pragma unroll
      for (int nt = 0; nt < 4; nt++){
        bf16x8 b = *(bf16x8*)&Es[nt*16 + m16][ks + quad*8];
        acc[nt] = __builtin_amdgcn_mfma_f32_16x16x32_bf16(a, b, acc[nt], 0, 0, 0);
      }
    }
    __syncthreads();
  }
  int rbase = r0 + w*16 + quad*4;
  f32x4 bi = *(const f32x4*)(b_ih + rbase);
  f32x4 bh = *(const f32x4*)(b_hh + rbase);
  #pragma unroll
  for (int nt = 0; nt < 4; nt++){
    int n = n0 + nt*16 + m16;
    f32x4 o = acc[nt] + bi + bh;
    *(f32x4*)(GX + n*4096 + rbase) = o;
  }
}

// ---------------- k_build
__global__ __launch_bounds__(64) void k_build(const float* __restrict__ SC,
                                              const int* __restrict__ length,
                                              int* __restrict__ LCH, int* __restrict__ RCH,
                                              int* __restrict__ LEVCNT, int* __restrict__ LEVLIST,
                                              int* __restrict__ ROOTP, int* __restrict__ MAXLEV,
                                              float* __restrict__ OUT){
  __shared__ float scl[64];
  __shared__ int stk_s[64], stk_e[64], order_l[64];
  __shared__ int isn_l[64], lev_l[64], ns_l[64], ne_l[64];
  int b = blockIdx.x;
  if (threadIdx.x < 64){
    scl[threadIdx.x] = SC[b*64 + threadIdx.x];
    isn_l[threadIdx.x] = 0;
  }
  __syncthreads();
  if (threadIdx.x == 0){
    int len = length[b];
    int cnt = 0, sp = 0;
    if (len >= 2){ stk_s[0] = 0; stk_e[0] = len; sp = 1; }
    while (sp > 0){
      sp--;
      int s = stk_s[sp], e = stk_e[sp];
      int pos = s; float mx = scl[s];
      for (int q = s+1; q < e; q++){ if (scl[q] > mx){ mx = scl[q]; pos = q; } }
      order_l[cnt++] = pos;
      int lq;
      if (pos - s <= 0) lq = -1;
      else if (pos - s == 1) lq = s;
      else { lq = s; float m2 = scl[s]; for (int q = s+1; q < pos; q++){ if (scl[q] > m2){ m2 = scl[q]; lq = q; } } }
      int rq;
      if (e - (pos+1) <= 0) rq = -1;
      else if (e - (pos+1) == 1) rq = pos+1;
      else { rq = pos+1; float m2 = scl[pos+1]; for (int q = pos+2; q < e; q++){ if (scl[q] > m2){ m2 = scl[q]; rq = q; } } }
      LCH[b*64 + pos] = lq; RCH[b*64 + pos] = rq;
      ns_l[pos] = s; ne_l[pos] = e; isn_l[pos] = 1;
      if (pos - s >= 2){ stk_s[sp] = s; stk_e[sp] = pos; sp++; }
      if (e - pos - 1 >= 2){ stk_s[sp] = pos+1; stk_e[sp] = e; sp++; }
    }
    for (int i = cnt-1; i >= 0; i--){
      int p = order_l[i];
      int lv = 0;
      int lq = LCH[b*64 + p];
      if (lq >= 0 && isn_l[lq]) lv = lev_l[lq] + 1;
      int rq = RCH[b*64 + p];
      if (rq >= 0 && isn_l[rq] && lev_l[rq] + 1 > lv) lv = lev_l[rq] + 1;
      lev_l[p] = lv;
      int slot = atomicAdd(&LEVCNT[lv], 1);
      LEVLIST[lv*512 + slot] = (b << 8) | p;
    }
    float lp = 0.f;
    for (int i = 0; i < cnt; i++){
      int p = order_l[i];
      int s = ns_l[p], e = ne_l[p];
      float mx = scl[s];
      for (int q = s+1; q < e; q++) mx = fmaxf(mx, scl[q]);
      float sum = 0.f;
      for (int q = s; q < e; q++) sum += expf(scl[q] - mx);
      lp += (float)(e - s) * (scl[p] - (mx + logf(sum)));
    }
    OUT[32768 + b] = lp;
    int rp;
    if (len <= 1) rp = 0;
    else { rp = 0; float m2 = scl[0]; for (int q = 1; q < len; q++){ if (scl[q] > m2){ m2 = scl[q]; rp = q; } } }
    ROOTP[b] = rp;
    if (cnt > 0) atomicMax(MAXLEV, lev_l[order_l[0]]);
  }
}

// ---------------- k_lstm (cooperative, 32 blocks x 512): weights in registers, hand barrier
__global__ __launch_bounds__(512, 2) void k_lstm(const float* __restrict__ w_hh,
      const float* __restrict__ GX, float* __restrict__ HS, float* __restrict__ CS,
      short* __restrict__ HG, int* __restrict__ BAR){
  __shared__ float EX[4][32][17];
  int bi = blockIdx.x;
  int w = threadIdx.x >> 6, lane = threadIdx.x & 63;
  int quad = lane >> 4, m16 = lane & 15;
  int gate = w >> 1, jhalf = w & 1;
  int j0 = bi*32;
  int row = gate*1024 + j0 + jhalf*16 + m16;
  bf16x8 Wf[32];
  #pragma unroll
  for (int ks = 0; ks < 32; ks++){
    const float* p = w_hh + row*1024 + ks*32 + quad*8;
    float4 a = *(const float4*)p;
    float4 b = *(const float4*)(p + 4);
    bf16x8 o;
    o[0]=f2bf(a.x); o[1]=f2bf(a.y); o[2]=f2bf(a.z); o[3]=f2bf(a.w);
    o[4]=f2bf(b.x); o[5]=f2bf(b.y); o[6]=f2bf(b.z); o[7]=f2bf(b.w);
    Wf[ks] = o;
  }
  int tid = threadIdx.x;
  int ojl = tid >> 4, ob = tid & 15;
  int oj = j0 + ojl;
  float creg = 0.f;
  int jloc_base = jhalf*16 + quad*4;
  int phase = 0;
  for (int t = 0; t < 64; t++){
    const short* HR = HG + (t & 1)*16384;
    short* HW = HG + ((t + 1) & 1)*16384;
    f32x4 acc = {0.f, 0.f, 0.f, 0.f};
    #pragma unroll
    for (int ks = 0; ks < 32; ks++){
      bf16x8 bf = *(const bf16x8*)(HR + (ks*4 + quad)*128 + m16*8);
      acc = __builtin_amdgcn_mfma_f32_16x16x32_bf16(Wf[ks], bf, acc, 0, 0, 0);
    }
    #pragma unroll
    for (int r = 0; r < 4; r++) EX[gate][jloc_base + r][m16] = acc[r];
    __syncthreads();
    const float* gx = GX + (ob*64 + t)*4096 + oj;
    float gi = EX[0][ojl][ob] + gx[0];
    float gf = EX[1][ojl][ob] + gx[1024];
    float gu = EX[2][ojl][ob] + gx[2048];
    float go = EX[3][ojl][ob] + gx[3072];
    float cc = sigf(gf)*creg + sigf(gi)*tanhf(gu);
    float hh = sigf(go)*tanhf(cc);
    creg = cc;
    HS[(ob*64 + t)*1024 + oj] = hh;
    CS[(ob*64 + t)*1024 + oj] = cc;
    HW[(oj >> 3)*128 + ob*8 + (oj & 7)] = f2bf(hh);
    gridbar(BAR, 32, &phase);
  }
}

// ---------------- k_tree (cooperative, 256 blocks x 256): all levels, hand barrier, fused root
__global__ __launch_bounds__(256, 2) void k_tree(const short* __restrict__ TLWB,
      const float* __restrict__ tl_b,
      float* __restrict__ HS, float* __restrict__ CS,
      const int* __restrict__ LCH, const int* __restrict__ RCH,
      const int* __restrict__ LEVCNT, const int* __restrict__ LEVLIST,
      const int* __restrict__ MAXLEV, float* __restrict__ G,
      const int* __restrict__ ROOTP, float* __restrict__ OUT,
      int* __restrict__ BAR){
  __shared__ short Ws[64][72];
  __shared__ short Hs[64][72];
  __shared__ int nb[64], nq0[64], nq1[64], nq2[64];
  int maxlev = MAXLEV[0];
  int lane = threadIdx.x & 63, w = threadIdx.x >> 6;
  int m16 = lane & 15, quad = lane >> 4;
  int srr = threadIdx.x >> 2, skk = (threadIdx.x & 3)*16;
  int phase = 0;
  for (int v = 0; v <= maxlev; v++){
    int nc = LEVCNT[v];
    int ntiles = (nc + 63) >> 6;
    int ntasks = ntiles * 96;
    for (int task = blockIdx.x; task < ntasks; task += gridDim.x){
      int r0 = (task % 96)*64;
      int n0 = (task / 96)*64;
      if (threadIdx.x < 64){
        int n = n0 + threadIdx.x;
        if (n < nc){
          int e = LEVLIST[v*512 + n];
          int bb = e >> 8, p = e & 255;
          nb[threadIdx.x] = bb;
          nq0[threadIdx.x] = LCH[bb*64 + p];
          nq1[threadIdx.x] = RCH[bb*64 + p];
          nq2[threadIdx.x] = p;
        } else {
          nb[threadIdx.x] = -1; nq0[threadIdx.x] = -1;
          nq1[threadIdx.x] = -1; nq2[threadIdx.x] = -1;
        }
      }
      __syncthreads();
      f32x4 acc[4] = {{0,0,0,0},{0,0,0,0},{0,0,0,0},{0,0,0,0}};
      for (int k0 = 0; k0 < 3072; k0 += 64){
        *(bf16x8*)&Ws[srr][skk]     = *(const bf16x8*)(TLWB + (r0 + srr)*3072 + k0 + skk);
        *(bf16x8*)&Ws[srr][skk + 8] = *(const bf16x8*)(TLWB + (r0 + srr)*3072 + k0 + skk + 8);
        int seg = k0 >> 10;
        int ko = (k0 & 1023) + skk;
        {
          int nl = srr;
          int bb = nb[nl];
          int q = (seg == 0) ? nq0[nl] : (seg == 1) ? nq1[nl] : nq2[nl];
          if (bb >= 0 && q >= 0){
            const float* hp = HS + (bb*64 + q)*1024 + ko;
            float4 a0 = *(const float4*)hp;
            float4 a1 = *(const float4*)(hp + 4);
            float4 a2 = *(const float4*)(hp + 8);
            float4 a3 = *(const float4*)(hp + 12);
            bf16x8 o0, o1;
            o0[0]=f2bf(a0.x); o0[1]=f2bf(a0.y); o0[2]=f2bf(a0.z); o0[3]=f2bf(a0.w);
            o0[4]=f2bf(a1.x); o0[5]=f2bf(a1.y); o0[6]=f2bf(a1.z); o0[7]=f2bf(a1.w);
            o1[0]=f2bf(a2.x); o1[1]=f2bf(a2.y); o1[2]=f2bf(a2.z); o1[3]=f2bf(a2.w);
            o1[4]=f2bf(a3.x); o1[5]=f2bf(a3.y); o1[6]=f2bf(a3.z); o1[7]=f2bf(a3.w);
            *(bf16x8*)&Hs[nl][skk]     = o0;
            *(bf16x8*)&Hs[nl][skk + 8] = o1;
          } else {
            bf16x8 z = {0,0,0,0,0,0,0,0};
            *(bf16x8*)&Hs[nl][skk]     = z;
            *(bf16x8*)&Hs[nl][skk + 8] = z;
          }
        }
        __syncthreads();
        #pragma unroll
        for (int ks = 0; ks < 64; ks += 32){
          bf16x8 a = *(bf16x8*)&Ws[w*16 + m16][ks + quad*8];
          #pragma unroll
          for (int nt = 0; nt < 4; nt++){
            bf16x8 b = *(bf16x8*)&Hs[nt*16 + m16][ks + quad*8];
            acc[nt] = __builtin_amdgcn_mfma_f32_16x16x32_bf16(a, b, acc[nt], 0, 0, 0);
          }
        }
        __syncthreads();
      }
      int rbase = r0 + w*16 + quad*4;
      #pragma unroll
      for (int nt = 0; nt < 4; nt++){
        int n = n0 + nt*16 + m16;
        if (n < nc) *(f32x4*)(G + n*6144 + rbase) = acc[nt];
      }
      __syncthreads();
    }
    gridbar(BAR, 256, &phase);
    int total = nc * 1024;
    for (int idx = blockIdx.x*256 + threadIdx.x; idx < total; idx += gridDim.x*256){
      int n = idx >> 10, j = idx & 1023;
      int e = LEVLIST[v*512 + n];
      int b = e >> 8, p = e & 255;
      const float* g = G + n*6144;
      float gi  = g[j]        + tl_b[j];
      float gfl = g[1024 + j] + tl_b[1024 + j];
      float gfr = g[2048 + j] + tl_b[2048 + j];
      float gfm = g[3072 + j] + tl_b[3072 + j];
      float gu  = g[4096 + j] + tl_b[4096 + j];
      float go  = g[5120 + j] + tl_b[5120 + j];
      int lq = LCH[b*64 + p], rq = RCH[b*64 + p];
      float cl = (lq >= 0) ? CS[(b*64 + lq)*1024 + j] : 0.f;
      float cr = (rq >= 0) ? CS[(b*64 + rq)*1024 + j] : 0.f;
      float cm = CS[(b*64 + p)*1024 + j];
      float c = sigf(gfl)*cl + sigf(gfr)*cr + sigf(gfm)*cm + sigf(gi)*tanhf(gu);
      float h = sigf(go)*tanhf(c);
      HS[(b*64 + p)*1024 + j] = h;
      CS[(b*64 + p)*1024 + j] = c;
    }
    gridbar(BAR, 256, &phase);
  }
  // fused root gather
  for (int idx = blockIdx.x*256 + threadIdx.x; idx < 32768; idx += gridDim.x*256){
    int half = idx >> 14;
    int b = (idx >> 10) & 15, j = idx & 1023;
    int rp = ROOTP[b];
    OUT[half*16384 + b*1024 + j] = half ? CS[(b*64 + rp)*1024 + j]
                                        : HS[(b*64 + rp)*1024 + j];
  }
}

extern "C" void kernel_launch(void* const* d_in, const int* in_sizes, int n_in,
                              void* d_out, int out_size, void* d_ws, size_t ws_size,
                              hipStream_t stream) {
  (void)in_sizes; (void)n_in; (void)out_size; (void)ws_size;
  const float* emb    = (const float*)d_in[0];
  const int*   length = (const int*)  d_in[2];
  const float* w_ih   = (const float*)d_in[3];
  const float* w_hh   = (const float*)d_in[4];
  const float* b_ih   = (const float*)d_in[5];
  const float* b_hh   = (const float*)d_in[6];
  const float* tl_w   = (const float*)d_in[7];
  const float* tl_b   = (const float*)d_in[8];
  const float* rk_w1  = (const float*)d_in[9];
  const float* rk_w2  = (const float*)d_in[10];
  float* OUT = (float*)d_out;

  float* ws_f = (float*)d_ws;
  short* TLWB = (short*)ws_f;               // 18,874,368 shorts
  float* GX   = ws_f + 9437184;             // 4,194,304 f (reused as G by tree)
  float* HS   = ws_f + 13631488;            // 1,048,576 f
  float* CS   = ws_f + 14680064;            // 1,048,576 f
  float* SC   = ws_f + 15728640;            // 1,024 f
  short* HG   = (short*)(ws_f + 15729664);  // 32,768 shorts
  int*   IW   = (int*)(ws_f + 15746048);
  int* LCH     = IW;
  int* RCH     = IW + 1024;
  int* LEVCNT  = IW + 2048;
  int* LEVLIST = IW + 2112;
  int* ROOTP   = IW + 34880;
  int* MAXLEV  = IW + 34896;
  int* BAR1    = IW + 34912;   // lstm barrier counter
  int* BAR2    = IW + 34928;   // tree barrier counter
  float* G = GX;

  k_zero<<<1, 512, 0, stream>>>(HG, LEVCNT, MAXLEV, BAR1, BAR2);
  k_cvtw<<<9216, 256, 0, stream>>>(tl_w, TLWB);
  k_rank<<<1024, 128, 0, stream>>>(emb, rk_w1, rk_w2, SC);
  k_gx<<<1024, 256, 0, stream>>>(emb, w_ih, b_ih, b_hh, GX);
  k_build<<<16, 64, 0, stream>>>(SC, length, LCH, RCH, LEVCNT, LEVLIST, ROOTP, MAXLEV, OUT);

  {
    void* args[] = { (void*)&w_hh, (void*)&GX, (void*)&HS, (void*)&CS, (void*)&HG,
                     (void*)&BAR1 };
    hipLaunchCooperativeKernel((const void*)k_lstm, dim3(32), dim3(512), args, 0, stream);
  }
  {
    void* args[] = { (void*)&TLWB, (void*)&tl_b, (void*)&HS, (void*)&CS,
                     (void*)&LCH, (void*)&RCH, (void*)&LEVCNT, (void*)&LEVLIST,
                     (void*)&MAXLEV, (void*)&G, (void*)&ROOTP, (void*)&OUT,
                     (void*)&BAR2 };
    hipLaunchCooperativeKernel((const void*)k_tree, dim3(256), dim3(256), args, 0, stream);
  }
}

// Round 6
// 1760.498 us; speedup vs baseline: 2.3913x; 1.2302x over previous
//
#include <hip/hip_runtime.h>

typedef __attribute__((ext_vector_type(8))) short bf16x8;
typedef __attribute__((ext_vector_type(4))) float f32x4;

__device__ __forceinline__ float fsig(float x){ return 1.0f/(1.0f + __expf(-x)); }
__device__ __forceinline__ float ftanh(float x){
  x = fminf(fmaxf(x, -15.f), 15.f);
  float e = __expf(2.f*x);
  return (e - 1.f)/(e + 1.f);
}

__device__ __forceinline__ short f2bf(float x){
  union { float f; unsigned u; } v; v.f = x;
  unsigned r = v.u + 0x7fffu + ((v.u >> 16) & 1u);
  return (short)(r >> 16);
}

// Agent-scope grid barrier: monotone counter, leader-spin. Proven in R5.
__device__ __forceinline__ void gridbar(int* cnt, int nb, int* phase){
  __syncthreads();
  if (threadIdx.x == 0){
    __threadfence();
    __hip_atomic_fetch_add(cnt, 1, __ATOMIC_RELEASE, __HIP_MEMORY_SCOPE_AGENT);
    int tgt = (*phase) * nb + nb;
    while (__hip_atomic_load(cnt, __ATOMIC_RELAXED, __HIP_MEMORY_SCOPE_AGENT) < tgt)
      __builtin_amdgcn_s_sleep(1);
    __threadfence();
  }
  __syncthreads();
  (*phase) += 1;
}

// ---------------- k_zero
__global__ __launch_bounds__(512) void k_zero(short* __restrict__ HG, int* __restrict__ LEVCNT,
                                              int* __restrict__ MAXLEV, int* __restrict__ NODECNT,
                                              int* __restrict__ BAR1, int* __restrict__ BAR2){
  for (int i = threadIdx.x; i < 32768; i += 512) HG[i] = 0;
  if (threadIdx.x < 64) LEVCNT[threadIdx.x] = 0;
  if (threadIdx.x == 64) MAXLEV[0] = 0;
  if (threadIdx.x == 65) NODECNT[0] = 0;
  if (threadIdx.x == 66) BAR1[0] = 0;
  if (threadIdx.x == 67) BAR2[0] = 0;
}

// ---------------- k_rank
__global__ __launch_bounds__(128) void k_rank(const float* __restrict__ emb,
                                              const float* __restrict__ w1,
                                              const float* __restrict__ w2,
                                              float* __restrict__ SC){
  int bl = blockIdx.x;
  int j  = threadIdx.x;
  const float* e = emb + bl*1024;
  const float* w = w1 + j*1024;
  float acc = 0.f;
  for (int k = 0; k < 1024; k += 4){
    float4 ev = *(const float4*)(e + k);
    float4 wv = *(const float4*)(w + k);
    acc += ev.x*wv.x + ev.y*wv.y + ev.z*wv.z + ev.w*wv.w;
  }
  float s = fmaxf(acc, 0.f) * w2[j];
  __shared__ float red[128];
  red[j] = s;
  __syncthreads();
  for (int st = 64; st > 0; st >>= 1){
    if (j < st) red[j] += red[j + st];
    __syncthreads();
  }
  if (j == 0) SC[bl] = red[0];
}

// ---------------- k_gx (MFMA bf16): GX[bl][r] = emb[bl]·w_ih[r] + b_ih[r] + b_hh[r]
__global__ __launch_bounds__(256) void k_gx(const float* __restrict__ emb,
                                            const float* __restrict__ w_ih,
                                            const float* __restrict__ b_ih,
                                            const float* __restrict__ b_hh,
                                            float* __restrict__ GX){
  __shared__ short Ws[64][72];
  __shared__ short Es[64][72];
  int mt = blockIdx.x >> 4;
  int nt4 = blockIdx.x & 15;
  int r0 = mt*64, n0 = nt4*64;
  int lane = threadIdx.x & 63, w = threadIdx.x >> 6;
  int m16 = lane & 15, quad = lane >> 4;
  int srr = threadIdx.x >> 2, skk = (threadIdx.x & 3)*16;
  f32x4 acc[4] = {{0,0,0,0},{0,0,0,0},{0,0,0,0},{0,0,0,0}};
  for (int k0 = 0; k0 < 1024; k0 += 64){
    #pragma unroll
    for (int i = 0; i < 4; i++){
      float4 v = *(const float4*)(w_ih + (r0 + srr)*1024 + k0 + skk + i*4);
      Ws[srr][skk + i*4 + 0] = f2bf(v.x); Ws[srr][skk + i*4 + 1] = f2bf(v.y);
      Ws[srr][skk + i*4 + 2] = f2bf(v.z); Ws[srr][skk + i*4 + 3] = f2bf(v.w);
      float4 u = *(const float4*)(emb + (n0 + srr)*1024 + k0 + skk + i*4);
      Es[srr][skk + i*4 + 0] = f2bf(u.x); Es[srr][skk + i*4 + 1] = f2bf(u.y);
      Es[srr][skk + i*4 + 2] = f2bf(u.z); Es[srr][skk + i*4 + 3] = f2bf(u.w);
    }
    __syncthreads();
    #pragma unroll
    for (int ks = 0; ks < 64; ks += 32){
      bf16x8 a = *(bf16x8*)&Ws[w*16 + m16][ks + quad*8];
      #pragma unroll
      for (int nt = 0; nt < 4; nt++){
        bf16x8 b = *(bf16x8*)&Es[nt*16 + m16][ks + quad*8];
        acc[nt] = __builtin_amdgcn_mfma_f32_16x16x32_bf16(a, b, acc[nt], 0, 0, 0);
      }
    }
    __syncthreads();
  }
  int rbase = r0 + w*16 + quad*4;
  f32x4 bi = *(const f32x4*)(b_ih + rbase);
  f32x4 bh = *(const f32x4*)(b_hh + rbase);
  #pragma unroll
  for (int nt = 0; nt < 4; nt++){
    int n = n0 + nt*16 + m16;
    f32x4 o = acc[nt] + bi + bh;
    *(f32x4*)(GX + n*4096 + rbase) = o;
  }
}

// ---------------- k_build: greedy tree, levels, eids, parent refs, lps
__global__ __launch_bounds__(64) void k_build(const float* __restrict__ SC,
                                              const int* __restrict__ length,
                                              int* __restrict__ LCH, int* __restrict__ RCH,
                                              int* __restrict__ ISNODE,
                                              int* __restrict__ LEVCNT, int* __restrict__ LEVLIST,
                                              int* __restrict__ LEVEID, int* __restrict__ EINFO,
                                              int* __restrict__ PARENTREF, int* __restrict__ NODECNT,
                                              int* __restrict__ ROOTP, int* __restrict__ MAXLEV,
                                              float* __restrict__ OUT){
  __shared__ float scl[64];
  __shared__ int stk_s[64], stk_e[64], order_l[64];
  __shared__ int isn_l[64], lev_l[64], ns_l[64], ne_l[64];
  __shared__ int par_l[64], seg_l[64], eid_l[64], slot_l[64];
  int b = blockIdx.x;
  if (threadIdx.x < 64){
    scl[threadIdx.x] = SC[b*64 + threadIdx.x];
    isn_l[threadIdx.x] = 0;
    par_l[threadIdx.x] = -1;
  }
  __syncthreads();
  if (threadIdx.x == 0){
    int len = length[b];
    int cnt = 0, sp = 0;
    if (len >= 2){ stk_s[0] = 0; stk_e[0] = len; sp = 1; }
    while (sp > 0){
      sp--;
      int s = stk_s[sp], e = stk_e[sp];
      int pos = s; float mx = scl[s];
      for (int q = s+1; q < e; q++){ if (scl[q] > mx){ mx = scl[q]; pos = q; } }
      order_l[cnt++] = pos;
      int lq;
      if (pos - s <= 0) lq = -1;
      else if (pos - s == 1) lq = s;
      else { lq = s; float m2 = scl[s]; for (int q = s+1; q < pos; q++){ if (scl[q] > m2){ m2 = scl[q]; lq = q; } } }
      int rq;
      if (e - (pos+1) <= 0) rq = -1;
      else if (e - (pos+1) == 1) rq = pos+1;
      else { rq = pos+1; float m2 = scl[pos+1]; for (int q = pos+2; q < e; q++){ if (scl[q] > m2){ m2 = scl[q]; rq = q; } } }
      LCH[b*64 + pos] = lq; RCH[b*64 + pos] = rq;
      if (lq >= 0){ par_l[lq] = pos; seg_l[lq] = 0; }
      if (rq >= 0){ par_l[rq] = pos; seg_l[rq] = 1; }
      ns_l[pos] = s; ne_l[pos] = e; isn_l[pos] = 1;
      if (pos - s >= 2){ stk_s[sp] = s; stk_e[sp] = pos; sp++; }
      if (e - pos - 1 >= 2){ stk_s[sp] = pos+1; stk_e[sp] = e; sp++; }
    }
    // levels bottom-up
    for (int i = cnt-1; i >= 0; i--){
      int p = order_l[i];
      int lv = 0;
      int lq = LCH[b*64 + p];
      if (lq >= 0 && isn_l[lq]) lv = lev_l[lq] + 1;
      int rq = RCH[b*64 + p];
      if (rq >= 0 && isn_l[rq] && lev_l[rq] + 1 > lv) lv = lev_l[rq] + 1;
      lev_l[p] = lv;
      int slot = atomicAdd(&LEVCNT[lv], 1);
      LEVLIST[lv*512 + slot] = (b << 8) | p;
      slot_l[p] = slot;
    }
    // eids + einfo + leveid
    for (int i = 0; i < cnt; i++){
      int p = order_l[i];
      int eid = atomicAdd(NODECNT, 1);
      eid_l[p] = eid;
      EINFO[eid] = (b << 8) | p;
      LEVEID[lev_l[p]*512 + slot_l[p]] = eid;
    }
    // parent refs (parents created before children in order_l)
    for (int i = 0; i < cnt; i++){
      int p = order_l[i];
      PARENTREF[eid_l[p]] = (par_l[p] >= 0) ? (eid_l[par_l[p]]*2 + seg_l[p]) : -1;
    }
    for (int i = 0; i < 64; i++) ISNODE[b*64 + i] = isn_l[i];
    // lps
    float lp = 0.f;
    for (int i = 0; i < cnt; i++){
      int p = order_l[i];
      int s = ns_l[p], e = ne_l[p];
      float mx = scl[s];
      for (int q = s+1; q < e; q++) mx = fmaxf(mx, scl[q]);
      float sum = 0.f;
      for (int q = s; q < e; q++) sum += expf(scl[q] - mx);
      lp += (float)(e - s) * (scl[p] - (mx + logf(sum)));
    }
    OUT[32768 + b] = lp;
    int rp;
    if (len <= 1) rp = 0;
    else { rp = 0; float m2 = scl[0]; for (int q = 1; q < len; q++){ if (scl[q] > m2){ m2 = scl[q]; rp = q; } } }
    ROOTP[b] = rp;
    if (cnt > 0) atomicMax(MAXLEV, lev_l[order_l[0]]);
  }
}

// ---------------- k_lstm (cooperative, 32 blocks x 512)
__global__ __launch_bounds__(512, 2) void k_lstm(const float* __restrict__ w_hh,
      const float* __restrict__ GX, float* __restrict__ HS, float* __restrict__ CS,
      short* __restrict__ HG, int* __restrict__ BAR){
  __shared__ float EX[4][32][17];
  int bi = blockIdx.x;
  int w = threadIdx.x >> 6, lane = threadIdx.x & 63;
  int quad = lane >> 4, m16 = lane & 15;
  int gate = w >> 1, jhalf = w & 1;
  int j0 = bi*32;
  int row = gate*1024 + j0 + jhalf*16 + m16;
  bf16x8 Wf[32];
  #pragma unroll
  for (int ks = 0; ks < 32; ks++){
    const float* p = w_hh + row*1024 + ks*32 + quad*8;
    float4 a = *(const float4*)p;
    float4 b = *(const float4*)(p + 4);
    bf16x8 o;
    o[0]=f2bf(a.x); o[1]=f2bf(a.y); o[2]=f2bf(a.z); o[3]=f2bf(a.w);
    o[4]=f2bf(b.x); o[5]=f2bf(b.y); o[6]=f2bf(b.z); o[7]=f2bf(b.w);
    Wf[ks] = o;
  }
  int tid = threadIdx.x;
  int ojl = tid >> 4, ob = tid & 15;
  int oj = j0 + ojl;
  float creg = 0.f;
  int jloc_base = jhalf*16 + quad*4;
  int phase = 0;
  for (int t = 0; t < 64; t++){
    const short* HR = HG + (t & 1)*16384;
    short* HW = HG + ((t + 1) & 1)*16384;
    f32x4 acc = {0.f, 0.f, 0.f, 0.f};
    #pragma unroll
    for (int ks = 0; ks < 32; ks++){
      bf16x8 bf = *(const bf16x8*)(HR + (ks*4 + quad)*128 + m16*8);
      acc = __builtin_amdgcn_mfma_f32_16x16x32_bf16(Wf[ks], bf, acc, 0, 0, 0);
    }
    #pragma unroll
    for (int r = 0; r < 4; r++) EX[gate][jloc_base + r][m16] = acc[r];
    __syncthreads();
    const float* gx = GX + (ob*64 + t)*4096 + oj;
    float gi = EX[0][ojl][ob] + gx[0];
    float gf = EX[1][ojl][ob] + gx[1024];
    float gu = EX[2][ojl][ob] + gx[2048];
    float go = EX[3][ojl][ob] + gx[3072];
    float cc = fsig(gf)*creg + fsig(gi)*ftanh(gu);
    float hh = fsig(go)*ftanh(cc);
    creg = cc;
    HS[(ob*64 + t)*1024 + oj] = hh;
    CS[(ob*64 + t)*1024 + oj] = cc;
    HW[(oj >> 3)*128 + ob*8 + (oj & 7)] = f2bf(hh);
    gridbar(BAR, 32, &phase);
  }
}

// ---------------- k_tree2 (cooperative, 256 blocks x 256): LDS-resident weights
// Block bi owns tl_w rows [bi*24, bi*24+24), bf16 in LDS (stride 3080 shorts).
// Per level: GEMM from HCAT (bf16, MFMA, no inner syncthreads) -> bar -> update
// (h,c + push h into parent's HCAT slot) -> bar. Root gather fused at end.
__global__ __launch_bounds__(256) void k_tree2(const float* __restrict__ tl_w,
      const float* __restrict__ tl_b,
      float* __restrict__ HS, float* __restrict__ CS,
      const int* __restrict__ LCH, const int* __restrict__ RCH,
      const int* __restrict__ ISNODE,
      const int* __restrict__ LEVCNT, const int* __restrict__ LEVLIST,
      const int* __restrict__ LEVEID, const int* __restrict__ EINFO,
      const int* __restrict__ PARENTREF, const int* __restrict__ NODECNT,
      const int* __restrict__ MAXLEV, short* __restrict__ HCAT,
      float* __restrict__ G,
      const int* __restrict__ ROOTP, float* __restrict__ OUT,
      int* __restrict__ BAR){
  extern __shared__ short WL[];   // 24 x 3080 shorts = 147,840 B
  int R0 = blockIdx.x * 24;
  // stage 0: load + convert this block's 24 weight rows (once)
  for (int g = threadIdx.x; g < 9216; g += 256){
    int rowi = g / 384;
    int col  = (g % 384) * 8;
    const float* p = tl_w + (R0 + rowi)*3072 + col;
    float4 a = *(const float4*)p;
    float4 b2 = *(const float4*)(p + 4);
    bf16x8 o;
    o[0]=f2bf(a.x); o[1]=f2bf(a.y); o[2]=f2bf(a.z); o[3]=f2bf(a.w);
    o[4]=f2bf(b2.x); o[5]=f2bf(b2.y); o[6]=f2bf(b2.z); o[7]=f2bf(b2.w);
    *(bf16x8*)&WL[rowi*3080 + col] = o;
  }
  __syncthreads();

  int phase = 0;
  // stage 0b: prefill HCAT (m-seg = leaf state; leaf/absent children segs)
  {
    int ncnt = NODECNT[0];
    int total = ncnt * 1024;
    for (int idx = blockIdx.x*256 + threadIdx.x; idx < total; idx += 65536){
      int eid = idx >> 10, j = idx & 1023;
      int e = EINFO[eid];
      int b = e >> 8, p = e & 255;
      HCAT[eid*3072 + 2048 + j] = f2bf(HS[(b*64 + p)*1024 + j]);
      int lq = LCH[b*64 + p];
      if (lq < 0)               HCAT[eid*3072 + j] = 0;
      else if (!ISNODE[b*64+lq]) HCAT[eid*3072 + j] = f2bf(HS[(b*64 + lq)*1024 + j]);
      int rq = RCH[b*64 + p];
      if (rq < 0)               HCAT[eid*3072 + 1024 + j] = 0;
      else if (!ISNODE[b*64+rq]) HCAT[eid*3072 + 1024 + j] = f2bf(HS[(b*64 + rq)*1024 + j]);
    }
  }
  gridbar(BAR, 256, &phase);

  int maxlev = MAXLEV[0];
  int lane = threadIdx.x & 63, w = threadIdx.x >> 6;
  int m16 = lane & 15, quad = lane >> 4;
  for (int v = 0; v <= maxlev; v++){
    int nc = LEVCNT[v];
    int ntiles = (nc + 15) >> 4;
    // GEMM: every block computes its 24 rows for all node tiles; waves split tiles
    for (int nt = w; nt < ntiles; nt += 4){
      int n = nt*16 + m16;
      int eid = (n < nc) ? LEVEID[v*512 + n] : 1023;
      const short* bp = HCAT + eid*3072 + quad*8;
      const short* a0p = &WL[m16*3080 + quad*8];
      const short* a1p = &WL[(16 + (m16 & 7))*3080 + quad*8];
      f32x4 acc0 = {0,0,0,0}, acc1 = {0,0,0,0};
      #pragma unroll 8
      for (int k0 = 0; k0 < 3072; k0 += 32){
        bf16x8 bf = *(const bf16x8*)(bp + k0);
        bf16x8 a0 = *(const bf16x8*)(a0p + k0);
        bf16x8 a1 = *(const bf16x8*)(a1p + k0);
        acc0 = __builtin_amdgcn_mfma_f32_16x16x32_bf16(a0, bf, acc0, 0, 0, 0);
        acc1 = __builtin_amdgcn_mfma_f32_16x16x32_bf16(a1, bf, acc1, 0, 0, 0);
      }
      if (n < nc){
        *(f32x4*)(G + n*6144 + R0 + quad*4) = acc0;           // rows R0..R0+15
        if (quad < 2)
          *(f32x4*)(G + n*6144 + R0 + 16 + quad*4) = acc1;    // rows R0+16..R0+23
      }
    }
    gridbar(BAR, 256, &phase);
    // update
    int total = nc * 1024;
    for (int idx = blockIdx.x*256 + threadIdx.x; idx < total; idx += 65536){
      int slot = idx >> 10, j = idx & 1023;
      int e = LEVLIST[v*512 + slot];
      int b = e >> 8, p = e & 255;
      const float* g = G + slot*6144;
      float gi  = g[j]        + tl_b[j];
      float gfl = g[1024 + j] + tl_b[1024 + j];
      float gfr = g[2048 + j] + tl_b[2048 + j];
      float gfm = g[3072 + j] + tl_b[3072 + j];
      float gu  = g[4096 + j] + tl_b[4096 + j];
      float go  = g[5120 + j] + tl_b[5120 + j];
      int lq = LCH[b*64 + p], rq = RCH[b*64 + p];
      float cl = (lq >= 0) ? CS[(b*64 + lq)*1024 + j] : 0.f;
      float cr = (rq >= 0) ? CS[(b*64 + rq)*1024 + j] : 0.f;
      float cm = CS[(b*64 + p)*1024 + j];
      float c = fsig(gfl)*cl + fsig(gfr)*cr + fsig(gfm)*cm + fsig(gi)*ftanh(gu);
      float h = fsig(go)*ftanh(c);
      HS[(b*64 + p)*1024 + j] = h;
      CS[(b*64 + p)*1024 + j] = c;
      int eid = LEVEID[v*512 + slot];
      int pr = PARENTREF[eid];
      if (pr >= 0)
        HCAT[(pr >> 1)*3072 + (pr & 1)*1024 + j] = f2bf(h);
    }
    gridbar(BAR, 256, &phase);
  }
  // fused root gather
  for (int idx = blockIdx.x*256 + threadIdx.x; idx < 32768; idx += 65536){
    int half = idx >> 14;
    int b = (idx >> 10) & 15, j = idx & 1023;
    int rp = ROOTP[b];
    OUT[half*16384 + b*1024 + j] = half ? CS[(b*64 + rp)*1024 + j]
                                        : HS[(b*64 + rp)*1024 + j];
  }
}

extern "C" void kernel_launch(void* const* d_in, const int* in_sizes, int n_in,
                              void* d_out, int out_size, void* d_ws, size_t ws_size,
                              hipStream_t stream) {
  (void)in_sizes; (void)n_in; (void)out_size; (void)ws_size;
  const float* emb    = (const float*)d_in[0];
  const int*   length = (const int*)  d_in[2];
  const float* w_ih   = (const float*)d_in[3];
  const float* w_hh   = (const float*)d_in[4];
  const float* b_ih   = (const float*)d_in[5];
  const float* b_hh   = (const float*)d_in[6];
  const float* tl_w   = (const float*)d_in[7];
  const float* tl_b   = (const float*)d_in[8];
  const float* rk_w1  = (const float*)d_in[9];
  const float* rk_w2  = (const float*)d_in[10];
  float* OUT = (float*)d_out;

  float* ws_f = (float*)d_ws;
  float* GX   = ws_f;                        // 4,194,304 f (reused as G by tree)
  float* HS   = ws_f + 4194304;              // 1,048,576 f
  float* CS   = ws_f + 5242880;              // 1,048,576 f
  short* HCAT = (short*)(ws_f + 6291456);    // 1024*3072 shorts = 1,572,864 f
  float* SC   = ws_f + 7864320;              // 1,024 f
  short* HG   = (short*)(ws_f + 7865344);    // 32,768 shorts = 16,384 f
  int*   IW   = (int*)(ws_f + 7881728);
  int* LCH      = IW;               // 1024
  int* RCH      = IW + 1024;        // 1024
  int* ISNODE   = IW + 2048;        // 1024
  int* LEVCNT   = IW + 3072;        // 64
  int* LEVLIST  = IW + 3136;        // 32768
  int* LEVEID   = IW + 35904;       // 32768
  int* EINFO    = IW + 68672;       // 1024
  int* PARENTREF= IW + 69696;       // 1024
  int* ROOTP    = IW + 70720;       // 16
  int* MAXLEV   = IW + 70736;
  int* NODECNT  = IW + 70737;
  int* BAR1     = IW + 70752;
  int* BAR2     = IW + 70768;
  float* G = GX;

  k_zero<<<1, 512, 0, stream>>>(HG, LEVCNT, MAXLEV, NODECNT, BAR1, BAR2);
  k_rank<<<1024, 128, 0, stream>>>(emb, rk_w1, rk_w2, SC);
  k_gx<<<1024, 256, 0, stream>>>(emb, w_ih, b_ih, b_hh, GX);
  k_build<<<16, 64, 0, stream>>>(SC, length, LCH, RCH, ISNODE, LEVCNT, LEVLIST,
                                 LEVEID, EINFO, PARENTREF, NODECNT, ROOTP, MAXLEV, OUT);

  {
    void* args[] = { (void*)&w_hh, (void*)&GX, (void*)&HS, (void*)&CS, (void*)&HG,
                     (void*)&BAR1 };
    hipLaunchCooperativeKernel((const void*)k_lstm, dim3(32), dim3(512), args, 0, stream);
  }
  {
    static int attr_set = 0;
    if (!attr_set){
      hipFuncSetAttribute((const void*)k_tree2,
                          hipFuncAttributeMaxDynamicSharedMemorySize, 147840);
      attr_set = 1;
    }
    void* args[] = { (void*)&tl_w, (void*)&tl_b, (void*)&HS, (void*)&CS,
                     (void*)&LCH, (void*)&RCH, (void*)&ISNODE,
                     (void*)&LEVCNT, (void*)&LEVLIST, (void*)&LEVEID, (void*)&EINFO,
                     (void*)&PARENTREF, (void*)&NODECNT, (void*)&MAXLEV,
                     (void*)&HCAT, (void*)&G, (void*)&ROOTP, (void*)&OUT,
                     (void*)&BAR2 };
    hipLaunchCooperativeKernel((const void*)k_tree2, dim3(256), dim3(256), args,
                               147840, stream);
  }
}

// Round 7
// 1213.086 us; speedup vs baseline: 3.4704x; 1.4513x over previous
//
#include <hip/hip_runtime.h>

typedef __attribute__((ext_vector_type(8))) short bf16x8;
typedef __attribute__((ext_vector_type(4))) float f32x4;

__device__ __forceinline__ float fsig(float x){ return 1.0f/(1.0f + __expf(-x)); }
__device__ __forceinline__ float ftanh(float x){
  x = fminf(fmaxf(x, -15.f), 15.f);
  float e = __expf(2.f*x);
  return (e - 1.f)/(e + 1.f);
}

__device__ __forceinline__ short f2bf(float x){
  union { float f; unsigned u; } v; v.f = x;
  unsigned r = v.u + 0x7fffu + ((v.u >> 16) & 1u);
  return (short)(r >> 16);
}

// Barrier with write-through discipline: callers must have made all cross-block
// visible stores with agent-scope atomic stores. Release = s_waitcnt(0) per
// thread (no wbl2). Acquire = agent acquire fence (invalidate-only).
__device__ __forceinline__ void fastbar(int* cnt, int nb, int* phase){
  asm volatile("" ::: "memory");
  __builtin_amdgcn_s_waitcnt(0);
  asm volatile("" ::: "memory");
  __syncthreads();
  if (threadIdx.x == 0){
    __hip_atomic_fetch_add(cnt, 1, __ATOMIC_RELAXED, __HIP_MEMORY_SCOPE_AGENT);
    int tgt = (*phase + 1) * nb;
    while (__hip_atomic_load(cnt, __ATOMIC_RELAXED, __HIP_MEMORY_SCOPE_AGENT) < tgt)
      __builtin_amdgcn_s_sleep(1);
    __builtin_amdgcn_fence(__ATOMIC_ACQUIRE, "agent");
  }
  __syncthreads();
  (*phase)++;
}

// Two-level barrier for 256 blocks: 16 groups x 16 blocks -> root.
__device__ __forceinline__ void treebar(int* grp, int* root, int* phase){
  asm volatile("" ::: "memory");
  __builtin_amdgcn_s_waitcnt(0);
  asm volatile("" ::: "memory");
  __syncthreads();
  if (threadIdx.x == 0){
    int g = blockIdx.x & 15;
    int old = __hip_atomic_fetch_add(&grp[g*16], 1, __ATOMIC_RELAXED, __HIP_MEMORY_SCOPE_AGENT);
    if ((old & 15) == 15)
      __hip_atomic_fetch_add(root, 1, __ATOMIC_RELAXED, __HIP_MEMORY_SCOPE_AGENT);
    int tgt = (*phase + 1) * 16;
    while (__hip_atomic_load(root, __ATOMIC_RELAXED, __HIP_MEMORY_SCOPE_AGENT) < tgt)
      __builtin_amdgcn_s_sleep(1);
    __builtin_amdgcn_fence(__ATOMIC_ACQUIRE, "agent");
  }
  __syncthreads();
  (*phase)++;
}

// ---------------- k_zero
__global__ __launch_bounds__(512) void k_zero(short* __restrict__ HG, int* __restrict__ LEVCNT,
                                              int* __restrict__ MAXLEV, int* __restrict__ NODECNT,
                                              int* __restrict__ BAR1, int* __restrict__ GRP,
                                              int* __restrict__ ROOT){
  for (int i = threadIdx.x; i < 32768; i += 512) HG[i] = 0;
  if (threadIdx.x < 64) LEVCNT[threadIdx.x] = 0;
  if (threadIdx.x == 64) MAXLEV[0] = 0;
  if (threadIdx.x == 65) NODECNT[0] = 0;
  if (threadIdx.x == 66) BAR1[0] = 0;
  if (threadIdx.x == 67) ROOT[0] = 0;
  if (threadIdx.x >= 128 && threadIdx.x < 384) GRP[threadIdx.x - 128] = 0;
}

// ---------------- k_rank
__global__ __launch_bounds__(128) void k_rank(const float* __restrict__ emb,
                                              const float* __restrict__ w1,
                                              const float* __restrict__ w2,
                                              float* __restrict__ SC){
  int bl = blockIdx.x;
  int j  = threadIdx.x;
  const float* e = emb + bl*1024;
  const float* w = w1 + j*1024;
  float acc = 0.f;
  for (int k = 0; k < 1024; k += 4){
    float4 ev = *(const float4*)(e + k);
    float4 wv = *(const float4*)(w + k);
    acc += ev.x*wv.x + ev.y*wv.y + ev.z*wv.z + ev.w*wv.w;
  }
  float s = fmaxf(acc, 0.f) * w2[j];
  __shared__ float red[128];
  red[j] = s;
  __syncthreads();
  for (int st = 64; st > 0; st >>= 1){
    if (j < st) red[j] += red[j + st];
    __syncthreads();
  }
  if (j == 0) SC[bl] = red[0];
}

// ---------------- k_gx (MFMA bf16): GX[bl][r] = emb[bl]·w_ih[r] + b_ih[r] + b_hh[r]
__global__ __launch_bounds__(256) void k_gx(const float* __restrict__ emb,
                                            const float* __restrict__ w_ih,
                                            const float* __restrict__ b_ih,
                                            const float* __restrict__ b_hh,
                                            float* __restrict__ GX){
  __shared__ short Ws[64][72];
  __shared__ short Es[64][72];
  int mt = blockIdx.x >> 4;
  int nt4 = blockIdx.x & 15;
  int r0 = mt*64, n0 = nt4*64;
  int lane = threadIdx.x & 63, w = threadIdx.x >> 6;
  int m16 = lane & 15, quad = lane >> 4;
  int srr = threadIdx.x >> 2, skk = (threadIdx.x & 3)*16;
  f32x4 acc[4] = {{0,0,0,0},{0,0,0,0},{0,0,0,0},{0,0,0,0}};
  for (int k0 = 0; k0 < 1024; k0 += 64){
    #pragma unroll
    for (int i = 0; i < 4; i++){
      float4 v = *(const float4*)(w_ih + (r0 + srr)*1024 + k0 + skk + i*4);
      Ws[srr][skk + i*4 + 0] = f2bf(v.x); Ws[srr][skk + i*4 + 1] = f2bf(v.y);
      Ws[srr][skk + i*4 + 2] = f2bf(v.z); Ws[srr][skk + i*4 + 3] = f2bf(v.w);
      float4 u = *(const float4*)(emb + (n0 + srr)*1024 + k0 + skk + i*4);
      Es[srr][skk + i*4 + 0] = f2bf(u.x); Es[srr][skk + i*4 + 1] = f2bf(u.y);
      Es[srr][skk + i*4 + 2] = f2bf(u.z); Es[srr][skk + i*4 + 3] = f2bf(u.w);
    }
    __syncthreads();
    #pragma unroll
    for (int ks = 0; ks < 64; ks += 32){
      bf16x8 a = *(bf16x8*)&Ws[w*16 + m16][ks + quad*8];
      #pragma unroll
      for (int nt = 0; nt < 4; nt++){
        bf16x8 b = *(bf16x8*)&Es[nt*16 + m16][ks + quad*8];
        acc[nt] = __builtin_amdgcn_mfma_f32_16x16x32_bf16(a, b, acc[nt], 0, 0, 0);
      }
    }
    __syncthreads();
  }
  int rbase = r0 + w*16 + quad*4;
  f32x4 bi = *(const f32x4*)(b_ih + rbase);
  f32x4 bh = *(const f32x4*)(b_hh + rbase);
  #pragma unroll
  for (int nt = 0; nt < 4; nt++){
    int n = n0 + nt*16 + m16;
    f32x4 o = acc[nt] + bi + bh;
    *(f32x4*)(GX + n*4096 + rbase) = o;
  }
}

// ---------------- k_build
__global__ __launch_bounds__(64) void k_build(const float* __restrict__ SC,
                                              const int* __restrict__ length,
                                              int* __restrict__ LCH, int* __restrict__ RCH,
                                              int* __restrict__ ISNODE,
                                              int* __restrict__ LEVCNT, int* __restrict__ LEVLIST,
                                              int* __restrict__ LEVEID, int* __restrict__ EINFO,
                                              int* __restrict__ PARENTREF, int* __restrict__ NODECNT,
                                              int* __restrict__ ROOTP, int* __restrict__ MAXLEV,
                                              float* __restrict__ OUT){
  __shared__ float scl[64];
  __shared__ int stk_s[64], stk_e[64], order_l[64];
  __shared__ int isn_l[64], lev_l[64], ns_l[64], ne_l[64];
  __shared__ int par_l[64], seg_l[64], eid_l[64], slot_l[64];
  int b = blockIdx.x;
  if (threadIdx.x < 64){
    scl[threadIdx.x] = SC[b*64 + threadIdx.x];
    isn_l[threadIdx.x] = 0;
    par_l[threadIdx.x] = -1;
  }
  __syncthreads();
  if (threadIdx.x == 0){
    int len = length[b];
    int cnt = 0, sp = 0;
    if (len >= 2){ stk_s[0] = 0; stk_e[0] = len; sp = 1; }
    while (sp > 0){
      sp--;
      int s = stk_s[sp], e = stk_e[sp];
      int pos = s; float mx = scl[s];
      for (int q = s+1; q < e; q++){ if (scl[q] > mx){ mx = scl[q]; pos = q; } }
      order_l[cnt++] = pos;
      int lq;
      if (pos - s <= 0) lq = -1;
      else if (pos - s == 1) lq = s;
      else { lq = s; float m2 = scl[s]; for (int q = s+1; q < pos; q++){ if (scl[q] > m2){ m2 = scl[q]; lq = q; } } }
      int rq;
      if (e - (pos+1) <= 0) rq = -1;
      else if (e - (pos+1) == 1) rq = pos+1;
      else { rq = pos+1; float m2 = scl[pos+1]; for (int q = pos+2; q < e; q++){ if (scl[q] > m2){ m2 = scl[q]; rq = q; } } }
      LCH[b*64 + pos] = lq; RCH[b*64 + pos] = rq;
      if (lq >= 0){ par_l[lq] = pos; seg_l[lq] = 0; }
      if (rq >= 0){ par_l[rq] = pos; seg_l[rq] = 1; }
      ns_l[pos] = s; ne_l[pos] = e; isn_l[pos] = 1;
      if (pos - s >= 2){ stk_s[sp] = s; stk_e[sp] = pos; sp++; }
      if (e - pos - 1 >= 2){ stk_s[sp] = pos+1; stk_e[sp] = e; sp++; }
    }
    for (int i = cnt-1; i >= 0; i--){
      int p = order_l[i];
      int lv = 0;
      int lq = LCH[b*64 + p];
      if (lq >= 0 && isn_l[lq]) lv = lev_l[lq] + 1;
      int rq = RCH[b*64 + p];
      if (rq >= 0 && isn_l[rq] && lev_l[rq] + 1 > lv) lv = lev_l[rq] + 1;
      lev_l[p] = lv;
      int slot = atomicAdd(&LEVCNT[lv], 1);
      LEVLIST[lv*512 + slot] = (b << 8) | p;
      slot_l[p] = slot;
    }
    for (int i = 0; i < cnt; i++){
      int p = order_l[i];
      int eid = atomicAdd(NODECNT, 1);
      eid_l[p] = eid;
      EINFO[eid] = (b << 8) | p;
      LEVEID[lev_l[p]*512 + slot_l[p]] = eid;
    }
    for (int i = 0; i < cnt; i++){
      int p = order_l[i];
      PARENTREF[eid_l[p]] = (par_l[p] >= 0) ? (eid_l[par_l[p]]*2 + seg_l[p]) : -1;
    }
    for (int i = 0; i < 64; i++) ISNODE[b*64 + i] = isn_l[i];
    float lp = 0.f;
    for (int i = 0; i < cnt; i++){
      int p = order_l[i];
      int s = ns_l[p], e = ne_l[p];
      float mx = scl[s];
      for (int q = s+1; q < e; q++) mx = fmaxf(mx, scl[q]);
      float sum = 0.f;
      for (int q = s; q < e; q++) sum += expf(scl[q] - mx);
      lp += (float)(e - s) * (scl[p] - (mx + logf(sum)));
    }
    OUT[32768 + b] = lp;
    int rp;
    if (len <= 1) rp = 0;
    else { rp = 0; float m2 = scl[0]; for (int q = 1; q < len; q++){ if (scl[q] > m2){ m2 = scl[q]; rp = q; } } }
    ROOTP[b] = rp;
    if (cnt > 0) atomicMax(MAXLEV, lev_l[order_l[0]]);
  }
}

// ---------------- k_lstm (cooperative, 32 blocks x 512)
__global__ __launch_bounds__(512, 2) void k_lstm(const float* __restrict__ w_hh,
      const float* __restrict__ GX, float* __restrict__ HS, float* __restrict__ CS,
      short* __restrict__ HG, int* __restrict__ BAR){
  __shared__ float EX[4][32][17];
  int bi = blockIdx.x;
  int w = threadIdx.x >> 6, lane = threadIdx.x & 63;
  int quad = lane >> 4, m16 = lane & 15;
  int gate = w >> 1, jhalf = w & 1;
  int j0 = bi*32;
  int row = gate*1024 + j0 + jhalf*16 + m16;
  bf16x8 Wf[32];
  #pragma unroll
  for (int ks = 0; ks < 32; ks++){
    const float* p = w_hh + row*1024 + ks*32 + quad*8;
    float4 a = *(const float4*)p;
    float4 b = *(const float4*)(p + 4);
    bf16x8 o;
    o[0]=f2bf(a.x); o[1]=f2bf(a.y); o[2]=f2bf(a.z); o[3]=f2bf(a.w);
    o[4]=f2bf(b.x); o[5]=f2bf(b.y); o[6]=f2bf(b.z); o[7]=f2bf(b.w);
    Wf[ks] = o;
  }
  int tid = threadIdx.x;
  int ojl = tid >> 4, ob = tid & 15;
  int oj = j0 + ojl;
  float creg = 0.f;
  int jloc_base = jhalf*16 + quad*4;
  int phase = 0;
  for (int t = 0; t < 64; t++){
    const short* HR = HG + (t & 1)*16384;
    short* HW = HG + ((t + 1) & 1)*16384;
    f32x4 acc = {0.f, 0.f, 0.f, 0.f};
    #pragma unroll
    for (int ks = 0; ks < 32; ks++){
      bf16x8 bf = *(const bf16x8*)(HR + (ks*4 + quad)*128 + m16*8);
      acc = __builtin_amdgcn_mfma_f32_16x16x32_bf16(Wf[ks], bf, acc, 0, 0, 0);
    }
    #pragma unroll
    for (int r = 0; r < 4; r++) EX[gate][jloc_base + r][m16] = acc[r];
    __syncthreads();
    const float* gx = GX + (ob*64 + t)*4096 + oj;
    float gi = EX[0][ojl][ob] + gx[0];
    float gf = EX[1][ojl][ob] + gx[1024];
    float gu = EX[2][ojl][ob] + gx[2048];
    float go = EX[3][ojl][ob] + gx[3072];
    float cc = fsig(gf)*creg + fsig(gi)*ftanh(gu);
    float hh = fsig(go)*ftanh(cc);
    creg = cc;
    HS[(ob*64 + t)*1024 + oj] = hh;
    CS[(ob*64 + t)*1024 + oj] = cc;
    __hip_atomic_store(&HW[(oj >> 3)*128 + ob*8 + (oj & 7)], f2bf(hh),
                       __ATOMIC_RELAXED, __HIP_MEMORY_SCOPE_AGENT);
    fastbar(BAR, 32, &phase);
  }
}

// ---------------- k_tree3 (cooperative, 256 blocks x 256)
// Block bi owns channels J=[bi*4,bi*4+4) x all 6 gates: 24 tl_w rows
// (row(g,c)=g*1024+bi*4+c), bf16 LDS-resident. Per level: per 16-node tile,
// MFMA gates -> in-wave LDS exchange -> per-lane (node,chan) update writing
// HS/CS + pushing h into parent HCAT (agent write-through). ONE barrier/level.
__global__ __launch_bounds__(256) void k_tree3(const float* __restrict__ tl_w,
      const float* __restrict__ tl_b,
      float* __restrict__ HS, float* __restrict__ CS,
      const int* __restrict__ LCH, const int* __restrict__ RCH,
      const int* __restrict__ ISNODE,
      const int* __restrict__ LEVCNT, const int* __restrict__ LEVLIST,
      const int* __restrict__ LEVEID, const int* __restrict__ EINFO,
      const int* __restrict__ PARENTREF, const int* __restrict__ NODECNT,
      const int* __restrict__ MAXLEV, short* __restrict__ HCAT,
      const int* __restrict__ ROOTP, float* __restrict__ OUT,
      int* __restrict__ GRP, int* __restrict__ ROOT){
  extern __shared__ short WL[];                 // 24 rows x 3080 shorts
  float* EXF = (float*)(WL + 24*3080);          // 4 waves x 400 floats
  int bi = blockIdx.x;
  int J0 = bi*4;
  for (int gidx = threadIdx.x; gidx < 24*384; gidx += 256){
    int ri = gidx / 384;
    int col = (gidx % 384)*8;
    int g = ri >> 2, c = ri & 3;
    const float* p = tl_w + (g*1024 + J0 + c)*3072 + col;
    float4 a = *(const float4*)p;
    float4 b2 = *(const float4*)(p + 4);
    bf16x8 o;
    o[0]=f2bf(a.x); o[1]=f2bf(a.y); o[2]=f2bf(a.z); o[3]=f2bf(a.w);
    o[4]=f2bf(b2.x); o[5]=f2bf(b2.y); o[6]=f2bf(b2.z); o[7]=f2bf(b2.w);
    *(bf16x8*)&WL[ri*3080 + col] = o;
  }
  int lane = threadIdx.x & 63, w = threadIdx.x >> 6;
  int m16 = lane & 15, quad = lane >> 4;
  int uj = J0 + quad;                 // this lane's update channel
  float tb[6];
  #pragma unroll
  for (int g = 0; g < 6; g++) tb[g] = tl_b[g*1024 + uj];
  __syncthreads();
  int phase = 0;
  // prefill HCAT (m-seg = leaf h; leaf/absent child segs)
  int ncnt = NODECNT[0];
  {
    int total = ncnt * 1024;
    for (int idx = bi*256 + threadIdx.x; idx < total; idx += 65536){
      int eid = idx >> 10, j = idx & 1023;
      int e = EINFO[eid]; int b = e >> 8, p = e & 255;
      __hip_atomic_store(&HCAT[eid*3072 + 2048 + j], f2bf(HS[(b*64 + p)*1024 + j]),
                         __ATOMIC_RELAXED, __HIP_MEMORY_SCOPE_AGENT);
      int lq = LCH[b*64 + p];
      if (lq < 0)
        __hip_atomic_store(&HCAT[eid*3072 + j], (short)0, __ATOMIC_RELAXED, __HIP_MEMORY_SCOPE_AGENT);
      else if (!ISNODE[b*64 + lq])
        __hip_atomic_store(&HCAT[eid*3072 + j], f2bf(HS[(b*64 + lq)*1024 + j]),
                           __ATOMIC_RELAXED, __HIP_MEMORY_SCOPE_AGENT);
      int rq = RCH[b*64 + p];
      if (rq < 0)
        __hip_atomic_store(&HCAT[eid*3072 + 1024 + j], (short)0, __ATOMIC_RELAXED, __HIP_MEMORY_SCOPE_AGENT);
      else if (!ISNODE[b*64 + rq])
        __hip_atomic_store(&HCAT[eid*3072 + 1024 + j], f2bf(HS[(b*64 + rq)*1024 + j]),
                           __ATOMIC_RELAXED, __HIP_MEMORY_SCOPE_AGENT);
    }
  }
  treebar(GRP, ROOT, &phase);
  int maxlev = MAXLEV[0];
  for (int v = 0; v <= maxlev; v++){
    int nc = LEVCNT[v];
    int ntiles = (nc + 15) >> 4;
    for (int nt = w; nt < ntiles; nt += 4){
      int n = nt*16 + m16;
      bool valid = (n < nc);
      int eid = valid ? LEVEID[v*512 + n] : 1023;
      int e   = valid ? LEVLIST[v*512 + n] : 0;
      int b = e >> 8, p = e & 255;
      int lq = valid ? LCH[b*64 + p] : -1;
      int rq = valid ? RCH[b*64 + p] : -1;
      int pr = valid ? PARENTREF[eid] : -1;
      float cl = (valid && lq >= 0) ? CS[(b*64 + lq)*1024 + uj] : 0.f;
      float cr = (valid && rq >= 0) ? CS[(b*64 + rq)*1024 + uj] : 0.f;
      float cm = valid ? CS[(b*64 + p)*1024 + uj] : 0.f;
      const short* bp  = HCAT + eid*3072 + quad*8;
      const short* a0p = WL + m16*3080 + quad*8;
      const short* a1p = WL + (16 + (m16 & 7))*3080 + quad*8;
      f32x4 acc0 = {0,0,0,0}, acc1 = {0,0,0,0};
      #pragma unroll 8
      for (int k0 = 0; k0 < 3072; k0 += 32){
        bf16x8 bf = *(const bf16x8*)(bp + k0);
        bf16x8 a0 = *(const bf16x8*)(a0p + k0);
        bf16x8 a1 = *(const bf16x8*)(a1p + k0);
        acc0 = __builtin_amdgcn_mfma_f32_16x16x32_bf16(a0, bf, acc0, 0, 0, 0);
        acc1 = __builtin_amdgcn_mfma_f32_16x16x32_bf16(a1, bf, acc1, 0, 0, 0);
      }
      // in-wave gate exchange: D row quad*4+r of acc0 = ri (g*4+c) 0..15;
      // acc1 rows map to ri 16+((quad*4+r)&7) (quads 2,3 duplicate 0,1)
      float* ex = EXF + w*400;
      #pragma unroll
      for (int r = 0; r < 4; r++) ex[m16*25 + quad*4 + r] = acc0[r];
      if (quad < 2){
        #pragma unroll
        for (int r = 0; r < 4; r++) ex[m16*25 + 16 + quad*4 + r] = acc1[r];
      }
      // update: lane = (node m16, channel quad)
      if (valid){
        float gv[6];
        #pragma unroll
        for (int g = 0; g < 6; g++) gv[g] = ex[m16*25 + g*4 + quad] + tb[g];
        float c = fsig(gv[1])*cl + fsig(gv[2])*cr + fsig(gv[3])*cm + fsig(gv[0])*ftanh(gv[4]);
        float h = fsig(gv[5])*ftanh(c);
        __hip_atomic_store(&HS[(b*64 + p)*1024 + uj], h, __ATOMIC_RELAXED, __HIP_MEMORY_SCOPE_AGENT);
        __hip_atomic_store(&CS[(b*64 + p)*1024 + uj], c, __ATOMIC_RELAXED, __HIP_MEMORY_SCOPE_AGENT);
        if (pr >= 0)
          __hip_atomic_store(&HCAT[(pr >> 1)*3072 + (pr & 1)*1024 + uj], f2bf(h),
                             __ATOMIC_RELAXED, __HIP_MEMORY_SCOPE_AGENT);
      }
    }
    treebar(GRP, ROOT, &phase);
  }
  // fused root gather
  for (int idx = bi*256 + threadIdx.x; idx < 32768; idx += 65536){
    int half = idx >> 14;
    int b = (idx >> 10) & 15, j = idx & 1023;
    int rp = ROOTP[b];
    OUT[half*16384 + b*1024 + j] = half ? CS[(b*64 + rp)*1024 + j]
                                        : HS[(b*64 + rp)*1024 + j];
  }
}

extern "C" void kernel_launch(void* const* d_in, const int* in_sizes, int n_in,
                              void* d_out, int out_size, void* d_ws, size_t ws_size,
                              hipStream_t stream) {
  (void)in_sizes; (void)n_in; (void)out_size; (void)ws_size;
  const float* emb    = (const float*)d_in[0];
  const int*   length = (const int*)  d_in[2];
  const float* w_ih   = (const float*)d_in[3];
  const float* w_hh   = (const float*)d_in[4];
  const float* b_ih   = (const float*)d_in[5];
  const float* b_hh   = (const float*)d_in[6];
  const float* tl_w   = (const float*)d_in[7];
  const float* tl_b   = (const float*)d_in[8];
  const float* rk_w1  = (const float*)d_in[9];
  const float* rk_w2  = (const float*)d_in[10];
  float* OUT = (float*)d_out;

  float* ws_f = (float*)d_ws;
  float* GX   = ws_f;                        // 4,194,304 f
  float* HS   = ws_f + 4194304;              // 1,048,576 f
  float* CS   = ws_f + 5242880;              // 1,048,576 f
  short* HCAT = (short*)(ws_f + 6291456);    // 1024*3072 shorts
  float* SC   = ws_f + 7864320;              // 1,024 f
  short* HG   = (short*)(ws_f + 7865344);    // 32,768 shorts
  int*   IW   = (int*)(ws_f + 7881728);
  int* LCH      = IW;               // 1024
  int* RCH      = IW + 1024;        // 1024
  int* ISNODE   = IW + 2048;        // 1024
  int* LEVCNT   = IW + 3072;        // 64
  int* LEVLIST  = IW + 3136;        // 32768
  int* LEVEID   = IW + 35904;       // 32768
  int* EINFO    = IW + 68672;       // 1024
  int* PARENTREF= IW + 69696;       // 1024
  int* ROOTP    = IW + 70720;       // 16
  int* MAXLEV   = IW + 70736;
  int* NODECNT  = IW + 70737;
  int* BAR1     = IW + 70752;
  int* GRP      = IW + 70784;       // 16 groups x stride 16 = 256 ints
  int* ROOT     = IW + 71056;

  k_zero<<<1, 512, 0, stream>>>(HG, LEVCNT, MAXLEV, NODECNT, BAR1, GRP, ROOT);
  k_rank<<<1024, 128, 0, stream>>>(emb, rk_w1, rk_w2, SC);
  k_gx<<<1024, 256, 0, stream>>>(emb, w_ih, b_ih, b_hh, GX);
  k_build<<<16, 64, 0, stream>>>(SC, length, LCH, RCH, ISNODE, LEVCNT, LEVLIST,
                                 LEVEID, EINFO, PARENTREF, NODECNT, ROOTP, MAXLEV, OUT);

  {
    void* args[] = { (void*)&w_hh, (void*)&GX, (void*)&HS, (void*)&CS, (void*)&HG,
                     (void*)&BAR1 };
    hipLaunchCooperativeKernel((const void*)k_lstm, dim3(32), dim3(512), args, 0, stream);
  }
  {
    hipFuncSetAttribute((const void*)k_tree3,
                        hipFuncAttributeMaxDynamicSharedMemorySize, 154240);
    void* args[] = { (void*)&tl_w, (void*)&tl_b, (void*)&HS, (void*)&CS,
                     (void*)&LCH, (void*)&RCH, (void*)&ISNODE,
                     (void*)&LEVCNT, (void*)&LEVLIST, (void*)&LEVEID, (void*)&EINFO,
                     (void*)&PARENTREF, (void*)&NODECNT, (void*)&MAXLEV,
                     (void*)&HCAT, (void*)&ROOTP, (void*)&OUT,
                     (void*)&GRP, (void*)&ROOT };
    hipLaunchCooperativeKernel((const void*)k_tree3, dim3(256), dim3(256), args,
                               154240, stream);
  }
}